// Round 4
// baseline (338.854 us; speedup 1.0000x reference)
//
#include <hip/hip_runtime.h>
#include <cmath>

typedef _Float16 half_t;
typedef _Float16 half8 __attribute__((ext_vector_type(8)));
typedef _Float16 half4v __attribute__((ext_vector_type(4)));
typedef float float4v __attribute__((ext_vector_type(4)));

#define LOG2E 1.44269504088896340736f

#define GLDS16(g, l)                                                                   \
    __builtin_amdgcn_global_load_lds((const __attribute__((address_space(1))) void*)(g), \
                                     (__attribute__((address_space(3))) void*)(l), 16, 0, 0)

// ---------------- cast fp32 -> fp16 ----------------
__global__ void cast_f32_f16(const float* __restrict__ in, half_t* __restrict__ out, int n) {
    int i = (blockIdx.x * blockDim.x + threadIdx.x) * 4;
    if (i >= n) return;
    float4 v = *(const float4*)(in + i);
    half4v o;
    o[0] = (half_t)v.x; o[1] = (half_t)v.y; o[2] = (half_t)v.z; o[3] = (half_t)v.w;
    *(half4v*)(out + i) = o;
}

// ---------------- transpose + cast: in fp32 [R][C] -> out fp16 [C][R] ----------------
__global__ void transpose_cast(const float* __restrict__ in, half_t* __restrict__ out, int R, int C) {
    __shared__ float tile[32][33];
    int c0 = blockIdx.x * 32, r0 = blockIdx.y * 32;
    int tx = threadIdx.x, ty = threadIdx.y; // block (32,8)
    for (int p = 0; p < 4; p++) {
        int r = r0 + ty + p * 8;
        tile[ty + p * 8][tx] = in[(size_t)r * C + c0 + tx];
    }
    __syncthreads();
    for (int p = 0; p < 4; p++) {
        int c = c0 + ty + p * 8;
        out[(size_t)c * R + r0 + tx] = (half_t)tile[tx][ty + p * 8];
    }
}

// ---------------- GEMM: C[M][N] = A[M][K] * Bt[N][K]^T + bias ----------------
// 128x128 tile, BK=32, 4 waves; m97-style global_load_lds width-16 staging.
// MODE 0: fp32 out + bias (output projection).
// MODE 1: fused QKV epilogue — n<2048: RMSNorm over each 64-wide head (fp32 accs)
//         then head-major store to Qh/Kh; n>=2048: plain fp16 store to qkvV.
template <int MODE>
__global__ __launch_bounds__(256) void gemm_f16(
    const half_t* __restrict__ A,   // [M][K]
    const half_t* __restrict__ Bt,  // [N][K]
    const float* __restrict__ bias, // [N]
    void* __restrict__ Cout,
    int M, int N, int K,
    const float* __restrict__ wq, const float* __restrict__ wk,
    half_t* __restrict__ Qh, half_t* __restrict__ Kh)
{
    __shared__ __align__(16) half_t As[128 * 32];
    __shared__ __align__(16) half_t Bs[128 * 32];
    int t = threadIdx.x;
    int lane = t & 63, w = t >> 6;
    int m0 = blockIdx.x * 128, n0 = blockIdx.y * 128;
    int wm = (w >> 1) * 64, wn = (w & 1) * 64;
    int lrow = lane & 15, quad = lane >> 4;

    int srow = t >> 2, scol = (t & 3) * 8;
    const half_t* gA = A  + (size_t)(m0 + srow) * K + scol;
    const half_t* gB = Bt + (size_t)(n0 + srow) * K + scol;
    half_t* ldsA = As + w * 512;
    half_t* ldsB = Bs + w * 512;

    float4v acc[4][4] = {};

    for (int k0 = 0; k0 < K; k0 += 32) {
        __syncthreads();
        GLDS16(gA + k0,                  ldsA);
        GLDS16(gA + (size_t)64 * K + k0, ldsA + 2048);
        GLDS16(gB + k0,                  ldsB);
        GLDS16(gB + (size_t)64 * K + k0, ldsB + 2048);
        __asm__ volatile("s_waitcnt vmcnt(0)" ::: "memory");
        __syncthreads();
        half8 af[4], bf[4];
        for (int i = 0; i < 4; i++) af[i] = *(const half8*)(&As[(wm + i * 16 + lrow) * 32 + quad * 8]);
        for (int i = 0; i < 4; i++) bf[i] = *(const half8*)(&Bs[(wn + i * 16 + lrow) * 32 + quad * 8]);
        for (int mi = 0; mi < 4; mi++)
            for (int ni = 0; ni < 4; ni++)
                acc[mi][ni] = __builtin_amdgcn_mfma_f32_16x16x32_f16(af[mi], bf[ni], acc[mi][ni], 0, 0, 0);
    }

    if (MODE == 0) {
        float* out = (float*)Cout;
        for (int mi = 0; mi < 4; mi++)
            for (int ni = 0; ni < 4; ni++)
                for (int r = 0; r < 4; r++) {
                    int gr = m0 + wm + mi * 16 + quad * 4 + r;
                    int gc = n0 + wn + ni * 16 + lrow;
                    out[(size_t)gr * N + gc] = acc[mi][ni][r] + bias[gc];
                }
    } else {
        int nglob = n0 + wn;            // 64-aligned; one head per wave
        if (nglob < 2048) {
            int isK = nglob >> 10;
            int h = (nglob >> 6) & 15;
            const float* wv = isK ? wk : wq;
            half_t* dst = isK ? Kh : Qh;
            for (int mi = 0; mi < 4; mi++)
                for (int r = 0; r < 4; r++) {
                    int gr = m0 + wm + mi * 16 + quad * 4 + r;
                    float v[4]; float ss = 0.f;
                    for (int ni = 0; ni < 4; ni++) {
                        v[ni] = acc[mi][ni][r] + bias[nglob + ni * 16 + lrow];
                        ss += v[ni] * v[ni];
                    }
                    ss += __shfl_xor(ss, 1);
                    ss += __shfl_xor(ss, 2);
                    ss += __shfl_xor(ss, 4);
                    ss += __shfl_xor(ss, 8);
                    float rr = rsqrtf(ss * (1.0f / 64.0f) + 1e-6f);
                    int bb = gr >> 11, s = gr & 2047;
                    size_t rowbase = ((size_t)((bb * 16 + h) * 2048 + s)) * 64;
                    for (int ni = 0; ni < 4; ni++) {
                        int d = ni * 16 + lrow;
                        dst[rowbase + d] = (half_t)(v[ni] * rr * wv[d]);
                    }
                }
        } else {
            half_t* qv = (half_t*)Cout;  // [8192][1024]
            for (int mi = 0; mi < 4; mi++)
                for (int ni = 0; ni < 4; ni++)
                    for (int r = 0; r < 4; r++) {
                        int gr = m0 + wm + mi * 16 + quad * 4 + r;
                        int gc = nglob + ni * 16 + lrow;
                        qv[(size_t)gr * 1024 + (gc - 2048)] = (half_t)(acc[mi][ni][r] + bias[gc]);
                    }
        }
    }
}

// ---------------- V relayout: qkvV [b*s][1024] -> Vt [bh][d][s] ----------------
__global__ void v_transpose(const half_t* __restrict__ qv, half_t* __restrict__ Vt) {
    __shared__ half_t tile[32][40];
    int s0 = blockIdx.x * 32;
    int d0 = blockIdx.y * 32;
    int bh = blockIdx.z;
    int b = bh >> 4, h = bh & 15;
    int tx = threadIdx.x, ty = threadIdx.y; // (32,8)
    for (int p = 0; p < 4; p++) {
        int s = s0 + ty + p * 8;
        tile[ty + p * 8][tx] = qv[((size_t)(b * 2048 + s)) * 1024 + h * 64 + d0 + tx];
    }
    __syncthreads();
    for (int p = 0; p < 4; p++) {
        int d = d0 + ty + p * 8;
        Vt[((size_t)bh * 64 + d) * 2048 + s0 + tx] = tile[tx][ty + p * 8];
    }
}

// ---------------- Flash attention, causal, no scale ----------------
// 16-wave blocks, paired q-tiles (i,15-i) sequentially -> uniform 17 staging iters.
// Wave pairs (w, w+8) share a 16-q strip and split keys even/odd 64-tiles;
// each iteration stages two k-tiles (one per group). Per-pass (m,l,O) merge in LDS.
// 512 blocks x 16 waves = 32 waves/CU; LDS 64KB -> 2 blocks/CU.
__global__ __launch_bounds__(1024, 8) void attn(
    const half_t* __restrict__ Qh, const half_t* __restrict__ Kh, const half_t* __restrict__ Vt,
    half_t* __restrict__ Z)
{
    __shared__ __align__(16) half_t smem[2 * 4096 + 2 * 4096 + 16 * 1024]; // 64 KB
    half_t* Ks = smem;              // [2][64*64] chunk-swizzled
    half_t* Vs = smem + 8192;       // [2][64*64] chunk-swizzled
    half_t* Ps = smem + 16384;      // [16][16*64] chunk-swizzled
    float*  sc = (float*)smem;          // merge O scratch: 8 strips x 1024 f (32 KB)
    float*  ml = (float*)(smem + 16384);// merge m,l: 8 strips x 128 f (4 KB)

    int bh = blockIdx.y;
    int b = bh >> 4, h = bh & 15;
    int t = threadIdx.x, lane = t & 63, w = t >> 6;
    int lrow = lane & 15, quad = lane >> 4;
    int grp = w >> 3, ws8 = w & 7;

    // staging: wave w stages 8 rows of tile (2*it+grp) into buffer grp
    int sr = ws8 * 8 + (lane >> 3);
    int scc = (lane & 7) ^ ((lane >> 3) & 7);
    const half_t* gK0 = Kh + ((size_t)bh * 2048 + sr) * 64 + scc * 8;
    const half_t* gV0 = Vt + ((size_t)bh * 64 + sr) * 2048 + scc * 8;
    half_t* ldsK = Ks + grp * 4096 + ws8 * 512;
    half_t* ldsV = Vs + grp * 4096 + ws8 * 512;
    const half_t* KsG = Ks + grp * 4096;
    const half_t* VsG = Vs + grp * 4096;

    int sw = lrow & 7;
    int cA = (quad ^ sw) * 8;
    int cB = ((quad + 4) ^ sw) * 8;
    half_t* PsW = Ps + w * 1024 + lrow * 64;

    for (int pass = 0; pass < 2; pass++) {
        int qt = pass ? (15 - (int)blockIdx.x) : (int)blockIdx.x;
        int q0w = qt * 128 + ws8 * 16;

        const half_t* Qbase = Qh + ((size_t)bh * 2048 + q0w + lrow) * 64;
        half8 qf0 = *(const half8*)(Qbase + quad * 8);
        half8 qf1 = *(const half8*)(Qbase + 32 + quad * 8);

        float4v ot[4] = {};
        float m = -__builtin_inff(), l = 0.f;

        int iters = qt + 1;
        for (int it = 0; it < iters; it++) {
            int kb = (2 * it + grp) * 64;
            __syncthreads();
            GLDS16(gK0 + (size_t)kb * 64, ldsK);
            GLDS16(gV0 + kb,              ldsV);
            __asm__ volatile("s_waitcnt vmcnt(0)" ::: "memory");
            __syncthreads();
            if (kb > q0w + 15) continue;   // fully masked for this wave

            // S^T = K Q^T : st[f] rows = keys kb+16f+quad*4+r, col q = lrow
            float4v st[4];
            for (int f = 0; f < 4; f++) {
                float4v z = {};
                const half_t* kr = KsG + (f * 16 + lrow) * 64;
                half8 k0 = *(const half8*)(kr + cA);
                half8 k1 = *(const half8*)(kr + cB);
                z = __builtin_amdgcn_mfma_f32_16x16x32_f16(k0, qf0, z, 0, 0, 0);
                z = __builtin_amdgcn_mfma_f32_16x16x32_f16(k1, qf1, z, 0, 0, 0);
                st[f] = z;
            }
            if (kb + 63 > q0w) {  // diagonal-crossing tile for this strip
                int qabs = q0w + lrow;
                for (int f = 0; f < 4; f++)
                    for (int r = 0; r < 4; r++) {
                        int key = kb + f * 16 + quad * 4 + r;
                        if (key > qabs) st[f][r] = -__builtin_inff();
                    }
            }
            float tm = st[0][0];
            for (int f = 0; f < 4; f++)
                for (int r = 0; r < 4; r++) tm = fmaxf(tm, st[f][r]);
            tm = fmaxf(tm, __shfl_xor(tm, 16));
            tm = fmaxf(tm, __shfl_xor(tm, 32));
            float mn = fmaxf(m, tm);
            float alpha = exp2f((m - mn) * LOG2E);
            m = mn;
            float rs = 0.f;
            for (int f = 0; f < 4; f++) {
                half4v ph;
                for (int r = 0; r < 4; r++) {
                    float p = exp2f((st[f][r] - mn) * LOG2E);
                    rs += p;
                    ph[r] = (half_t)p;
                }
                int cc = (2 * f + (quad >> 1)) ^ sw;
                *(half4v*)(PsW + cc * 8 + (quad & 1) * 4) = ph;
            }
            rs += __shfl_xor(rs, 16);
            rs += __shfl_xor(rs, 32);
            l = l * alpha + rs;
            for (int f2 = 0; f2 < 4; f2++)
                for (int r = 0; r < 4; r++) ot[f2][r] *= alpha;

            __asm__ volatile("s_waitcnt lgkmcnt(0)" ::: "memory");
            half8 p0 = *(const half8*)(PsW + cA);
            half8 p1 = *(const half8*)(PsW + cB);
            for (int f2 = 0; f2 < 4; f2++) {
                const half_t* vr = VsG + (f2 * 16 + lrow) * 64;
                half8 v0 = *(const half8*)(vr + cA);
                half8 v1 = *(const half8*)(vr + cB);
                ot[f2] = __builtin_amdgcn_mfma_f32_16x16x32_f16(v0, p0, ot[f2], 0, 0, 0);
                ot[f2] = __builtin_amdgcn_mfma_f32_16x16x32_f16(v1, p1, ot[f2], 0, 0, 0);
            }
        }

        // merge wave pair (w, w+8): disjoint key sets over the same strip
        __syncthreads();
        if (grp == 1) {
            for (int f = 0; f < 4; f++)
                *(float4v*)(sc + ws8 * 1024 + lane * 16 + f * 4) = ot[f];
            ml[ws8 * 128 + lane * 2]     = m;
            ml[ws8 * 128 + lane * 2 + 1] = l;
        }
        __syncthreads();
        if (grp == 0) {
            float m2 = ml[ws8 * 128 + lane * 2];
            float l2 = ml[ws8 * 128 + lane * 2 + 1];
            float mn = fmaxf(m, m2);            // m is finite (group A always has tile 0)
            float a1 = exp2f((m - mn) * LOG2E);
            float a2 = exp2f((m2 - mn) * LOG2E);
            float inv = 1.0f / (l * a1 + l2 * a2);
            size_t base = ((size_t)(b * 2048) + q0w + lrow) * 1024 + h * 64;
            for (int f2 = 0; f2 < 4; f2++) {
                float4v o2 = *(const float4v*)(sc + ws8 * 1024 + lane * 16 + f2 * 4);
                half4v oh;
                for (int r = 0; r < 4; r++)
                    oh[r] = (half_t)((ot[f2][r] * a1 + o2[r] * a2) * inv);
                *(half4v*)(Z + base + f2 * 16 + quad * 4) = oh;
            }
        }
    }
}

// ---------------- launch ----------------
extern "C" void kernel_launch(void* const* d_in, const int* in_sizes, int n_in,
                              void* d_out, int out_size, void* d_ws, size_t ws_size,
                              hipStream_t stream)
{
    const float* x     = (const float*)d_in[0];
    // d_in[1] = mask (causal, known analytically) - unused
    const float* W_qkv = (const float*)d_in[2];
    const float* b_qkv = (const float*)d_in[3];
    const float* W_o   = (const float*)d_in[4];
    const float* b_o   = (const float*)d_in[5];
    const float* wq    = (const float*)d_in[6];
    const float* wk    = (const float*)d_in[7];
    float* out = (float*)d_out;

    char* ws = (char*)d_ws;
    half_t* xh   = (half_t*)(ws);                     // 16 MB (reused as zh after attn)
    half_t* Wqt  = (half_t*)(ws + (16ull << 20));     // 6 MB
    half_t* Wot  = (half_t*)(ws + (22ull << 20));     // 2 MB
    half_t* qkvV = (half_t*)(ws + (24ull << 20));     // 16 MB (v-part only)
    half_t* Qh   = (half_t*)(ws + (40ull << 20));     // 16 MB
    half_t* Kh   = (half_t*)(ws + (56ull << 20));     // 16 MB
    half_t* Vt   = (half_t*)(ws + (72ull << 20));     // 16 MB
    half_t* zh   = xh;

    cast_f32_f16<<<8192, 256, 0, stream>>>(x, xh, 8192 * 1024);
    transpose_cast<<<dim3(96, 32), dim3(32, 8), 0, stream>>>(W_qkv, Wqt, 1024, 3072);
    transpose_cast<<<dim3(32, 32), dim3(32, 8), 0, stream>>>(W_o, Wot, 1024, 1024);
    gemm_f16<1><<<dim3(64, 24), 256, 0, stream>>>(xh, Wqt, b_qkv, qkvV, 8192, 3072, 1024,
                                                  wq, wk, Qh, Kh);
    v_transpose<<<dim3(64, 2, 64), dim3(32, 8), 0, stream>>>(qkvV, Vt);
    attn<<<dim3(8, 64), 1024, 0, stream>>>(Qh, Kh, Vt, zh);
    gemm_f16<0><<<dim3(64, 8), 256, 0, stream>>>(zh, Wot, b_o, out, 8192, 1024, 1024,
                                                 nullptr, nullptr, nullptr, nullptr);
}

// Round 5
// 313.325 us; speedup vs baseline: 1.0815x; 1.0815x over previous
//
#include <hip/hip_runtime.h>
#include <cmath>

typedef _Float16 half_t;
typedef _Float16 half8 __attribute__((ext_vector_type(8)));
typedef _Float16 half4v __attribute__((ext_vector_type(4)));
typedef float float4v __attribute__((ext_vector_type(4)));

#define LOG2E 1.44269504088896340736f

#define GLDS16(g, l)                                                                   \
    __builtin_amdgcn_global_load_lds((const __attribute__((address_space(1))) void*)(g), \
                                     (__attribute__((address_space(3))) void*)(l), 16, 0, 0)

// ---------------- cast fp32 -> fp16 ----------------
__global__ void cast_f32_f16(const float* __restrict__ in, half_t* __restrict__ out, int n) {
    int i = (blockIdx.x * blockDim.x + threadIdx.x) * 4;
    if (i >= n) return;
    float4 v = *(const float4*)(in + i);
    half4v o;
    o[0] = (half_t)v.x; o[1] = (half_t)v.y; o[2] = (half_t)v.z; o[3] = (half_t)v.w;
    *(half4v*)(out + i) = o;
}

// ---------------- transpose + cast: in fp32 [R][C] -> out fp16 [C][R] ----------------
__global__ void transpose_cast(const float* __restrict__ in, half_t* __restrict__ out, int R, int C) {
    __shared__ float tile[32][33];
    int c0 = blockIdx.x * 32, r0 = blockIdx.y * 32;
    int tx = threadIdx.x, ty = threadIdx.y; // block (32,8)
    for (int p = 0; p < 4; p++) {
        int r = r0 + ty + p * 8;
        tile[ty + p * 8][tx] = in[(size_t)r * C + c0 + tx];
    }
    __syncthreads();
    for (int p = 0; p < 4; p++) {
        int c = c0 + ty + p * 8;
        out[(size_t)c * R + r0 + tx] = (half_t)tile[tx][ty + p * 8];
    }
}

// ---------------- GEMM: C[M][N] = A[M][K] * Bt[N][K]^T + bias ----------------
// 128x128 tile, BK=32, 4 waves; m97-style global_load_lds width-16 staging.
// MODE 0: fp32 out + bias (output projection).
// MODE 1: fused QKV epilogue — n<2048: RMSNorm over each 64-wide head (fp32 accs)
//         then head-major store to Qh/Kh; n>=2048: plain fp16 store to qkvV.
template <int MODE>
__global__ __launch_bounds__(256) void gemm_f16(
    const half_t* __restrict__ A,   // [M][K]
    const half_t* __restrict__ Bt,  // [N][K]
    const float* __restrict__ bias, // [N]
    void* __restrict__ Cout,
    int M, int N, int K,
    const float* __restrict__ wq, const float* __restrict__ wk,
    half_t* __restrict__ Qh, half_t* __restrict__ Kh)
{
    __shared__ __align__(16) half_t As[128 * 32];
    __shared__ __align__(16) half_t Bs[128 * 32];
    int t = threadIdx.x;
    int lane = t & 63, w = t >> 6;
    int m0 = blockIdx.x * 128, n0 = blockIdx.y * 128;
    int wm = (w >> 1) * 64, wn = (w & 1) * 64;
    int lrow = lane & 15, quad = lane >> 4;

    int srow = t >> 2, scol = (t & 3) * 8;
    const half_t* gA = A  + (size_t)(m0 + srow) * K + scol;
    const half_t* gB = Bt + (size_t)(n0 + srow) * K + scol;
    half_t* ldsA = As + w * 512;
    half_t* ldsB = Bs + w * 512;

    float4v acc[4][4] = {};

    for (int k0 = 0; k0 < K; k0 += 32) {
        __syncthreads();
        GLDS16(gA + k0,                  ldsA);
        GLDS16(gA + (size_t)64 * K + k0, ldsA + 2048);
        GLDS16(gB + k0,                  ldsB);
        GLDS16(gB + (size_t)64 * K + k0, ldsB + 2048);
        __asm__ volatile("s_waitcnt vmcnt(0)" ::: "memory");
        __syncthreads();
        half8 af[4], bf[4];
        for (int i = 0; i < 4; i++) af[i] = *(const half8*)(&As[(wm + i * 16 + lrow) * 32 + quad * 8]);
        for (int i = 0; i < 4; i++) bf[i] = *(const half8*)(&Bs[(wn + i * 16 + lrow) * 32 + quad * 8]);
        for (int mi = 0; mi < 4; mi++)
            for (int ni = 0; ni < 4; ni++)
                acc[mi][ni] = __builtin_amdgcn_mfma_f32_16x16x32_f16(af[mi], bf[ni], acc[mi][ni], 0, 0, 0);
    }

    if (MODE == 0) {
        float* out = (float*)Cout;
        for (int mi = 0; mi < 4; mi++)
            for (int ni = 0; ni < 4; ni++)
                for (int r = 0; r < 4; r++) {
                    int gr = m0 + wm + mi * 16 + quad * 4 + r;
                    int gc = n0 + wn + ni * 16 + lrow;
                    out[(size_t)gr * N + gc] = acc[mi][ni][r] + bias[gc];
                }
    } else {
        int nglob = n0 + wn;            // 64-aligned; one head per wave
        if (nglob < 2048) {
            int isK = nglob >> 10;
            int h = (nglob >> 6) & 15;
            const float* wv = isK ? wk : wq;
            half_t* dst = isK ? Kh : Qh;
            for (int mi = 0; mi < 4; mi++)
                for (int r = 0; r < 4; r++) {
                    int gr = m0 + wm + mi * 16 + quad * 4 + r;
                    float v[4]; float ss = 0.f;
                    for (int ni = 0; ni < 4; ni++) {
                        v[ni] = acc[mi][ni][r] + bias[nglob + ni * 16 + lrow];
                        ss += v[ni] * v[ni];
                    }
                    ss += __shfl_xor(ss, 1);
                    ss += __shfl_xor(ss, 2);
                    ss += __shfl_xor(ss, 4);
                    ss += __shfl_xor(ss, 8);
                    float rr = rsqrtf(ss * (1.0f / 64.0f) + 1e-6f);
                    int bb = gr >> 11, s = gr & 2047;
                    size_t rowbase = ((size_t)((bb * 16 + h) * 2048 + s)) * 64;
                    for (int ni = 0; ni < 4; ni++) {
                        int d = ni * 16 + lrow;
                        dst[rowbase + d] = (half_t)(v[ni] * rr * wv[d]);
                    }
                }
        } else {
            half_t* qv = (half_t*)Cout;  // [8192][1024]
            for (int mi = 0; mi < 4; mi++)
                for (int ni = 0; ni < 4; ni++)
                    for (int r = 0; r < 4; r++) {
                        int gr = m0 + wm + mi * 16 + quad * 4 + r;
                        int gc = nglob + ni * 16 + lrow;
                        qv[(size_t)gr * 1024 + (gc - 2048)] = (half_t)(acc[mi][ni][r] + bias[gc]);
                    }
        }
    }
}

// ---------------- V relayout: qkvV [b*s][1024] -> Vt [bh][d][s] ----------------
__global__ void v_transpose(const half_t* __restrict__ qv, half_t* __restrict__ Vt) {
    __shared__ half_t tile[32][40];
    int s0 = blockIdx.x * 32;
    int d0 = blockIdx.y * 32;
    int bh = blockIdx.z;
    int b = bh >> 4, h = bh & 15;
    int tx = threadIdx.x, ty = threadIdx.y; // (32,8)
    for (int p = 0; p < 4; p++) {
        int s = s0 + ty + p * 8;
        tile[ty + p * 8][tx] = qv[((size_t)(b * 2048 + s)) * 1024 + h * 64 + d0 + tx];
    }
    __syncthreads();
    for (int p = 0; p < 4; p++) {
        int d = d0 + ty + p * 8;
        Vt[((size_t)bh * 64 + d) * 2048 + s0 + tx] = tile[tx][ty + p * 8];
    }
}

// ---------------- Flash attention, causal, no scale ----------------
// r3 shape (8 waves / 128 q-rows, paired q-tiles (i,15-i), XOR-swizzled LDS) plus:
//  * grid (bh, pair) so same-bh blocks share an XCD's L2 (linear%8 == bh%8)
//  * double-buffered K/V global_load_lds with s_waitcnt vmcnt(2) (never 0 mid-loop)
__global__ __launch_bounds__(512, 4) void attn(
    const half_t* __restrict__ Qh, const half_t* __restrict__ Kh, const half_t* __restrict__ Vt,
    half_t* __restrict__ Z)
{
    __shared__ __align__(16) half_t Ks[2][64 * 64];   // [buf][key][d], chunk-swizzled
    __shared__ __align__(16) half_t Vs[2][64 * 64];   // [buf][d][key], chunk-swizzled
    __shared__ __align__(16) half_t Ps[8 * 16 * 64];  // per-wave [q][key], chunk-swizzled

    int bh = blockIdx.x;
    int b = bh >> 4, h = bh & 15;
    int t = threadIdx.x, lane = t & 63, w = t >> 6;
    int lrow = lane & 15, quad = lane >> 4;

    // staging: thread covers (row sr, stored chunk lane&7) -> loads logical chunk scc
    int sr = w * 8 + (lane >> 3);
    int scc = (lane & 7) ^ ((lane >> 3) & 7);
    const half_t* gK0 = Kh + ((size_t)bh * 2048 + sr) * 64 + scc * 8;
    const half_t* gV0 = Vt + ((size_t)bh * 64 + sr) * 2048 + scc * 8;

    int sw = lrow & 7;
    int cA = (quad ^ sw) * 8;
    int cB = ((quad + 4) ^ sw) * 8;
    half_t* PsW = Ps + w * 1024 + lrow * 64;

    for (int pass = 0; pass < 2; pass++) {
        int qt = pass ? (15 - (int)blockIdx.y) : (int)blockIdx.y;
        int q0w = qt * 128 + w * 16;

        const half_t* Qbase = Qh + ((size_t)bh * 2048 + q0w + lrow) * 64;
        half8 qf0 = *(const half8*)(Qbase + quad * 8);
        half8 qf1 = *(const half8*)(Qbase + 32 + quad * 8);

        float4v ot[4] = {};
        float m = -__builtin_inff(), l = 0.f;

        int nt = 2 * qt + 2;
        // preload tile 0 -> buf 0 (barrier first: prior pass readers of buf 0)
        __syncthreads();
        GLDS16(gK0, &Ks[0][w * 512]);
        GLDS16(gV0, &Vs[0][w * 512]);

        for (int kt = 0; kt < nt; kt++) {
            int cur = kt & 1, nxt = cur ^ 1;
            int kb = kt * 64;
            __syncthreads();   // readers of buf nxt (iter kt-1) are done
            if (kt + 1 < nt) {
                GLDS16(gK0 + (size_t)(kb + 64) * 64, &Ks[nxt][w * 512]);
                GLDS16(gV0 + kb + 64,                &Vs[nxt][w * 512]);
                __asm__ volatile("s_waitcnt vmcnt(2)" ::: "memory");
            } else {
                __asm__ volatile("s_waitcnt vmcnt(0)" ::: "memory");
            }
            __syncthreads();   // all waves' buf cur ready
            if (kb > q0w + 15) continue;   // fully masked for this wave

            // S^T = K Q^T : st[f] rows = keys kb+16f+quad*4+r, col q = lrow
            float4v st[4];
            for (int f = 0; f < 4; f++) {
                float4v z = {};
                const half_t* kr = &Ks[cur][(f * 16 + lrow) * 64];
                half8 k0 = *(const half8*)(kr + cA);
                half8 k1 = *(const half8*)(kr + cB);
                z = __builtin_amdgcn_mfma_f32_16x16x32_f16(k0, qf0, z, 0, 0, 0);
                z = __builtin_amdgcn_mfma_f32_16x16x32_f16(k1, qf1, z, 0, 0, 0);
                st[f] = z;
            }
            if (kb + 63 > q0w) {  // diagonal-crossing tile for this strip
                int qabs = q0w + lrow;
                for (int f = 0; f < 4; f++)
                    for (int r = 0; r < 4; r++) {
                        int key = kb + f * 16 + quad * 4 + r;
                        if (key > qabs) st[f][r] = -__builtin_inff();
                    }
            }
            // online softmax: in-lane over 16 + 2 cross-quad shfls
            float tm = st[0][0];
            for (int f = 0; f < 4; f++)
                for (int r = 0; r < 4; r++) tm = fmaxf(tm, st[f][r]);
            tm = fmaxf(tm, __shfl_xor(tm, 16));
            tm = fmaxf(tm, __shfl_xor(tm, 32));
            float mn = fmaxf(m, tm);
            float alpha = exp2f((m - mn) * LOG2E);
            m = mn;
            float rs = 0.f;
            for (int f = 0; f < 4; f++) {
                half4v ph;
                for (int r = 0; r < 4; r++) {
                    float p = exp2f((st[f][r] - mn) * LOG2E);
                    rs += p;
                    ph[r] = (half_t)p;
                }
                int cc = (2 * f + (quad >> 1)) ^ sw;
                *(half4v*)(PsW + cc * 8 + (quad & 1) * 4) = ph;
            }
            rs += __shfl_xor(rs, 16);
            rs += __shfl_xor(rs, 32);
            l = l * alpha + rs;
            for (int f2 = 0; f2 < 4; f2++)
                for (int r = 0; r < 4; r++) ot[f2][r] *= alpha;

            __asm__ volatile("s_waitcnt lgkmcnt(0)" ::: "memory");
            half8 p0 = *(const half8*)(PsW + cA);
            half8 p1 = *(const half8*)(PsW + cB);
            for (int f2 = 0; f2 < 4; f2++) {
                const half_t* vr = &Vs[cur][(f2 * 16 + lrow) * 64];
                half8 v0 = *(const half8*)(vr + cA);
                half8 v1 = *(const half8*)(vr + cB);
                ot[f2] = __builtin_amdgcn_mfma_f32_16x16x32_f16(v0, p0, ot[f2], 0, 0, 0);
                ot[f2] = __builtin_amdgcn_mfma_f32_16x16x32_f16(v1, p1, ot[f2], 0, 0, 0);
            }
        }

        float inv = 1.0f / l;
        size_t base = ((size_t)(b * 2048) + q0w + lrow) * 1024 + h * 64;
        for (int f2 = 0; f2 < 4; f2++) {
            half4v oh;
            for (int r = 0; r < 4; r++) oh[r] = (half_t)(ot[f2][r] * inv);
            *(half4v*)(Z + base + f2 * 16 + quad * 4) = oh;
        }
    }
}

// ---------------- launch ----------------
extern "C" void kernel_launch(void* const* d_in, const int* in_sizes, int n_in,
                              void* d_out, int out_size, void* d_ws, size_t ws_size,
                              hipStream_t stream)
{
    const float* x     = (const float*)d_in[0];
    // d_in[1] = mask (causal, known analytically) - unused
    const float* W_qkv = (const float*)d_in[2];
    const float* b_qkv = (const float*)d_in[3];
    const float* W_o   = (const float*)d_in[4];
    const float* b_o   = (const float*)d_in[5];
    const float* wq    = (const float*)d_in[6];
    const float* wk    = (const float*)d_in[7];
    float* out = (float*)d_out;

    char* ws = (char*)d_ws;
    half_t* xh   = (half_t*)(ws);                     // 16 MB (reused as zh after attn)
    half_t* Wqt  = (half_t*)(ws + (16ull << 20));     // 6 MB
    half_t* Wot  = (half_t*)(ws + (22ull << 20));     // 2 MB
    half_t* qkvV = (half_t*)(ws + (24ull << 20));     // 16 MB (v-part only)
    half_t* Qh   = (half_t*)(ws + (40ull << 20));     // 16 MB
    half_t* Kh   = (half_t*)(ws + (56ull << 20));     // 16 MB
    half_t* Vt   = (half_t*)(ws + (72ull << 20));     // 16 MB
    half_t* zh   = xh;

    cast_f32_f16<<<8192, 256, 0, stream>>>(x, xh, 8192 * 1024);
    transpose_cast<<<dim3(96, 32), dim3(32, 8), 0, stream>>>(W_qkv, Wqt, 1024, 3072);
    transpose_cast<<<dim3(32, 32), dim3(32, 8), 0, stream>>>(W_o, Wot, 1024, 1024);
    gemm_f16<1><<<dim3(64, 24), 256, 0, stream>>>(xh, Wqt, b_qkv, qkvV, 8192, 3072, 1024,
                                                  wq, wk, Qh, Kh);
    v_transpose<<<dim3(64, 2, 64), dim3(32, 8), 0, stream>>>(qkvV, Vt);
    attn<<<dim3(64, 8), 512, 0, stream>>>(Qh, Kh, Vt, zh);
    gemm_f16<0><<<dim3(64, 8), 256, 0, stream>>>(zh, Wot, b_o, out, 8192, 1024, 1024,
                                                 nullptr, nullptr, nullptr, nullptr);
}

// Round 6
// 306.148 us; speedup vs baseline: 1.1068x; 1.0234x over previous
//
#include <hip/hip_runtime.h>
#include <cmath>

typedef _Float16 half_t;
typedef _Float16 half8 __attribute__((ext_vector_type(8)));
typedef _Float16 half4v __attribute__((ext_vector_type(4)));
typedef float float4v __attribute__((ext_vector_type(4)));

#define LOG2E 1.44269504088896340736f

#define GLDS16(g, l)                                                                   \
    __builtin_amdgcn_global_load_lds((const __attribute__((address_space(1))) void*)(g), \
                                     (__attribute__((address_space(3))) void*)(l), 16, 0, 0)

// ---------------- cast fp32 -> fp16 ----------------
__global__ void cast_f32_f16(const float* __restrict__ in, half_t* __restrict__ out, int n) {
    int i = (blockIdx.x * blockDim.x + threadIdx.x) * 4;
    if (i >= n) return;
    float4 v = *(const float4*)(in + i);
    half4v o;
    o[0] = (half_t)v.x; o[1] = (half_t)v.y; o[2] = (half_t)v.z; o[3] = (half_t)v.w;
    *(half4v*)(out + i) = o;
}

// ---------------- transpose + cast: in fp32 [R][C] -> out fp16 [C][R] ----------------
__global__ void transpose_cast(const float* __restrict__ in, half_t* __restrict__ out, int R, int C) {
    __shared__ float tile[32][33];
    int c0 = blockIdx.x * 32, r0 = blockIdx.y * 32;
    int tx = threadIdx.x, ty = threadIdx.y; // block (32,8)
    for (int p = 0; p < 4; p++) {
        int r = r0 + ty + p * 8;
        tile[ty + p * 8][tx] = in[(size_t)r * C + c0 + tx];
    }
    __syncthreads();
    for (int p = 0; p < 4; p++) {
        int c = c0 + ty + p * 8;
        out[(size_t)c * R + r0 + tx] = (half_t)tile[tx][ty + p * 8];
    }
}

// ---------------- GEMM: C[M][N] = A[M][K] * Bt[N][K]^T + bias ----------------
// 128x128 tile, BK=32, 4 waves; double-buffered global_load_lds staging
// (issue next tile, s_waitcnt vmcnt(4) -> loads in flight a full iteration).
// MODE 0: fp32 out + bias (output projection).
// MODE 1: fused QKV epilogue — n<2048: RMSNorm per 64-wide head -> Qh/Kh
//         head-major; n>=2048: V part stored TRANSPOSED directly into Vt[bh][d][s].
template <int MODE>
__global__ __launch_bounds__(256) void gemm_f16(
    const half_t* __restrict__ A,   // [M][K]
    const half_t* __restrict__ Bt,  // [N][K]
    const float* __restrict__ bias, // [N]
    void* __restrict__ Cout,
    int M, int N, int K,
    const float* __restrict__ wq, const float* __restrict__ wk,
    half_t* __restrict__ Qh, half_t* __restrict__ Kh)
{
    __shared__ __align__(16) half_t As[2][128 * 32];
    __shared__ __align__(16) half_t Bs[2][128 * 32];
    int t = threadIdx.x;
    int lane = t & 63, w = t >> 6;
    int m0 = blockIdx.x * 128, n0 = blockIdx.y * 128;
    int wm = (w >> 1) * 64, wn = (w & 1) * 64;
    int lrow = lane & 15, quad = lane >> 4;

    int srow = t >> 2, scol = (t & 3) * 8;
    const half_t* gA = A  + (size_t)(m0 + srow) * K + scol;
    const half_t* gB = Bt + (size_t)(n0 + srow) * K + scol;
    half_t* ldsA[2] = { &As[0][w * 512], &As[1][w * 512] };
    half_t* ldsB[2] = { &Bs[0][w * 512], &Bs[1][w * 512] };

    float4v acc[4][4] = {};

    // preload tile 0 -> buf 0
    GLDS16(gA,                  ldsA[0]);
    GLDS16(gA + (size_t)64 * K, ldsA[0] + 2048);
    GLDS16(gB,                  ldsB[0]);
    GLDS16(gB + (size_t)64 * K, ldsB[0] + 2048);

    for (int k0 = 0; k0 < K; k0 += 32) {
        int cur = (k0 >> 5) & 1, nxt = cur ^ 1;
        __syncthreads();                    // readers of buf nxt (prev iter) done
        if (k0 + 32 < K) {
            GLDS16(gA + k0 + 32,                  ldsA[nxt]);
            GLDS16(gA + (size_t)64 * K + k0 + 32, ldsA[nxt] + 2048);
            GLDS16(gB + k0 + 32,                  ldsB[nxt]);
            GLDS16(gB + (size_t)64 * K + k0 + 32, ldsB[nxt] + 2048);
            __asm__ volatile("s_waitcnt vmcnt(4)" ::: "memory");
        } else {
            __asm__ volatile("s_waitcnt vmcnt(0)" ::: "memory");
        }
        __syncthreads();                    // every wave's buf cur complete
        half8 af[4], bf[4];
        for (int i = 0; i < 4; i++) af[i] = *(const half8*)(&As[cur][(wm + i * 16 + lrow) * 32 + quad * 8]);
        for (int i = 0; i < 4; i++) bf[i] = *(const half8*)(&Bs[cur][(wn + i * 16 + lrow) * 32 + quad * 8]);
        for (int mi = 0; mi < 4; mi++)
            for (int ni = 0; ni < 4; ni++)
                acc[mi][ni] = __builtin_amdgcn_mfma_f32_16x16x32_f16(af[mi], bf[ni], acc[mi][ni], 0, 0, 0);
    }

    if (MODE == 0) {
        float* out = (float*)Cout;
        for (int mi = 0; mi < 4; mi++)
            for (int ni = 0; ni < 4; ni++)
                for (int r = 0; r < 4; r++) {
                    int gr = m0 + wm + mi * 16 + quad * 4 + r;
                    int gc = n0 + wn + ni * 16 + lrow;
                    out[(size_t)gr * N + gc] = acc[mi][ni][r] + bias[gc];
                }
    } else {
        int nglob = n0 + wn;            // 64-aligned; one head per wave
        if (nglob < 2048) {
            int isK = nglob >> 10;
            int h = (nglob >> 6) & 15;
            const float* wv = isK ? wk : wq;
            half_t* dst = isK ? Kh : Qh;
            for (int mi = 0; mi < 4; mi++)
                for (int r = 0; r < 4; r++) {
                    int gr = m0 + wm + mi * 16 + quad * 4 + r;
                    float v[4]; float ss = 0.f;
                    for (int ni = 0; ni < 4; ni++) {
                        v[ni] = acc[mi][ni][r] + bias[nglob + ni * 16 + lrow];
                        ss += v[ni] * v[ni];
                    }
                    ss += __shfl_xor(ss, 1);
                    ss += __shfl_xor(ss, 2);
                    ss += __shfl_xor(ss, 4);
                    ss += __shfl_xor(ss, 8);
                    float rr = rsqrtf(ss * (1.0f / 64.0f) + 1e-6f);
                    int bb = gr >> 11, s = gr & 2047;
                    size_t rowbase = ((size_t)((bb * 16 + h) * 2048 + s)) * 64;
                    for (int ni = 0; ni < 4; ni++) {
                        int d = ni * 16 + lrow;
                        dst[rowbase + d] = (half_t)(v[ni] * rr * wv[d]);
                    }
                }
        } else {
            // V part: store transposed into Vt[bh][d][s] (4 consecutive s per lane)
            half_t* Vt = (half_t*)Cout;
            for (int mi = 0; mi < 4; mi++) {
                int gr = m0 + wm + mi * 16 + quad * 4;   // s-base, 4-aligned
                int bb = gr >> 11, s = gr & 2047;
                for (int ni = 0; ni < 4; ni++) {
                    int dg = nglob + ni * 16 + lrow - 2048;   // 0..1023
                    float bv = bias[nglob + ni * 16 + lrow];
                    half4v oh;
                    for (int r = 0; r < 4; r++) oh[r] = (half_t)(acc[mi][ni][r] + bv);
                    *(half4v*)(Vt + ((size_t)((bb * 16 + (dg >> 6)) * 64 + (dg & 63))) * 2048 + s) = oh;
                }
            }
        }
    }
}

// ---------------- Flash attention, causal, no scale ----------------
// 8 waves / 128 q-rows, paired q-tiles (i,15-i), XOR-swizzled LDS,
// grid (bh, pair) for XCD L2 sharing, double-buffered K/V with vmcnt(2).
__global__ __launch_bounds__(512, 4) void attn(
    const half_t* __restrict__ Qh, const half_t* __restrict__ Kh, const half_t* __restrict__ Vt,
    half_t* __restrict__ Z)
{
    __shared__ __align__(16) half_t Ks[2][64 * 64];   // [buf][key][d], chunk-swizzled
    __shared__ __align__(16) half_t Vs[2][64 * 64];   // [buf][d][key], chunk-swizzled
    __shared__ __align__(16) half_t Ps[8 * 16 * 64];  // per-wave [q][key], chunk-swizzled

    int bh = blockIdx.x;
    int b = bh >> 4, h = bh & 15;
    int t = threadIdx.x, lane = t & 63, w = t >> 6;
    int lrow = lane & 15, quad = lane >> 4;

    int sr = w * 8 + (lane >> 3);
    int scc = (lane & 7) ^ ((lane >> 3) & 7);
    const half_t* gK0 = Kh + ((size_t)bh * 2048 + sr) * 64 + scc * 8;
    const half_t* gV0 = Vt + ((size_t)bh * 64 + sr) * 2048 + scc * 8;

    int sw = lrow & 7;
    int cA = (quad ^ sw) * 8;
    int cB = ((quad + 4) ^ sw) * 8;
    half_t* PsW = Ps + w * 1024 + lrow * 64;

    for (int pass = 0; pass < 2; pass++) {
        int qt = pass ? (15 - (int)blockIdx.y) : (int)blockIdx.y;
        int q0w = qt * 128 + w * 16;

        const half_t* Qbase = Qh + ((size_t)bh * 2048 + q0w + lrow) * 64;
        half8 qf0 = *(const half8*)(Qbase + quad * 8);
        half8 qf1 = *(const half8*)(Qbase + 32 + quad * 8);

        float4v ot[4] = {};
        float m = -__builtin_inff(), l = 0.f;

        int nt = 2 * qt + 2;
        __syncthreads();
        GLDS16(gK0, &Ks[0][w * 512]);
        GLDS16(gV0, &Vs[0][w * 512]);

        for (int kt = 0; kt < nt; kt++) {
            int cur = kt & 1, nxt = cur ^ 1;
            int kb = kt * 64;
            __syncthreads();
            if (kt + 1 < nt) {
                GLDS16(gK0 + (size_t)(kb + 64) * 64, &Ks[nxt][w * 512]);
                GLDS16(gV0 + kb + 64,                &Vs[nxt][w * 512]);
                __asm__ volatile("s_waitcnt vmcnt(2)" ::: "memory");
            } else {
                __asm__ volatile("s_waitcnt vmcnt(0)" ::: "memory");
            }
            __syncthreads();
            if (kb > q0w + 15) continue;

            float4v st[4];
            for (int f = 0; f < 4; f++) {
                float4v z = {};
                const half_t* kr = &Ks[cur][(f * 16 + lrow) * 64];
                half8 k0 = *(const half8*)(kr + cA);
                half8 k1 = *(const half8*)(kr + cB);
                z = __builtin_amdgcn_mfma_f32_16x16x32_f16(k0, qf0, z, 0, 0, 0);
                z = __builtin_amdgcn_mfma_f32_16x16x32_f16(k1, qf1, z, 0, 0, 0);
                st[f] = z;
            }
            if (kb + 63 > q0w) {
                int qabs = q0w + lrow;
                for (int f = 0; f < 4; f++)
                    for (int r = 0; r < 4; r++) {
                        int key = kb + f * 16 + quad * 4 + r;
                        if (key > qabs) st[f][r] = -__builtin_inff();
                    }
            }
            float tm = st[0][0];
            for (int f = 0; f < 4; f++)
                for (int r = 0; r < 4; r++) tm = fmaxf(tm, st[f][r]);
            tm = fmaxf(tm, __shfl_xor(tm, 16));
            tm = fmaxf(tm, __shfl_xor(tm, 32));
            float mn = fmaxf(m, tm);
            float alpha = exp2f((m - mn) * LOG2E);
            m = mn;
            float rs = 0.f;
            for (int f = 0; f < 4; f++) {
                half4v ph;
                for (int r = 0; r < 4; r++) {
                    float p = exp2f((st[f][r] - mn) * LOG2E);
                    rs += p;
                    ph[r] = (half_t)p;
                }
                int cc = (2 * f + (quad >> 1)) ^ sw;
                *(half4v*)(PsW + cc * 8 + (quad & 1) * 4) = ph;
            }
            rs += __shfl_xor(rs, 16);
            rs += __shfl_xor(rs, 32);
            l = l * alpha + rs;
            for (int f2 = 0; f2 < 4; f2++)
                for (int r = 0; r < 4; r++) ot[f2][r] *= alpha;

            __asm__ volatile("s_waitcnt lgkmcnt(0)" ::: "memory");
            half8 p0 = *(const half8*)(PsW + cA);
            half8 p1 = *(const half8*)(PsW + cB);
            for (int f2 = 0; f2 < 4; f2++) {
                const half_t* vr = &Vs[cur][(f2 * 16 + lrow) * 64];
                half8 v0 = *(const half8*)(vr + cA);
                half8 v1 = *(const half8*)(vr + cB);
                ot[f2] = __builtin_amdgcn_mfma_f32_16x16x32_f16(v0, p0, ot[f2], 0, 0, 0);
                ot[f2] = __builtin_amdgcn_mfma_f32_16x16x32_f16(v1, p1, ot[f2], 0, 0, 0);
            }
        }

        float inv = 1.0f / l;
        size_t base = ((size_t)(b * 2048) + q0w + lrow) * 1024 + h * 64;
        for (int f2 = 0; f2 < 4; f2++) {
            half4v oh;
            for (int r = 0; r < 4; r++) oh[r] = (half_t)(ot[f2][r] * inv);
            *(half4v*)(Z + base + f2 * 16 + quad * 4) = oh;
        }
    }
}

// ---------------- launch ----------------
extern "C" void kernel_launch(void* const* d_in, const int* in_sizes, int n_in,
                              void* d_out, int out_size, void* d_ws, size_t ws_size,
                              hipStream_t stream)
{
    const float* x     = (const float*)d_in[0];
    // d_in[1] = mask (causal, known analytically) - unused
    const float* W_qkv = (const float*)d_in[2];
    const float* b_qkv = (const float*)d_in[3];
    const float* W_o   = (const float*)d_in[4];
    const float* b_o   = (const float*)d_in[5];
    const float* wq    = (const float*)d_in[6];
    const float* wk    = (const float*)d_in[7];
    float* out = (float*)d_out;

    char* ws = (char*)d_ws;
    half_t* xh   = (half_t*)(ws);                     // 16 MB (reused as zh after attn)
    half_t* Wqt  = (half_t*)(ws + (16ull << 20));     // 6 MB
    half_t* Wot  = (half_t*)(ws + (22ull << 20));     // 2 MB
    half_t* Qh   = (half_t*)(ws + (40ull << 20));     // 16 MB
    half_t* Kh   = (half_t*)(ws + (56ull << 20));     // 16 MB
    half_t* Vt   = (half_t*)(ws + (72ull << 20));     // 16 MB
    half_t* zh   = xh;

    cast_f32_f16<<<8192, 256, 0, stream>>>(x, xh, 8192 * 1024);
    transpose_cast<<<dim3(96, 32), dim3(32, 8), 0, stream>>>(W_qkv, Wqt, 1024, 3072);
    transpose_cast<<<dim3(32, 32), dim3(32, 8), 0, stream>>>(W_o, Wot, 1024, 1024);
    gemm_f16<1><<<dim3(64, 24), 256, 0, stream>>>(xh, Wqt, b_qkv, Vt, 8192, 3072, 1024,
                                                  wq, wk, Qh, Kh);
    attn<<<dim3(64, 8), 512, 0, stream>>>(Qh, Kh, Vt, zh);
    gemm_f16<0><<<dim3(64, 8), 256, 0, stream>>>(zh, Wot, b_o, out, 8192, 1024, 1024,
                                                 nullptr, nullptr, nullptr, nullptr);
}

// Round 8
// 284.729 us; speedup vs baseline: 1.1901x; 1.0752x over previous
//
#include <hip/hip_runtime.h>
#include <cmath>

typedef _Float16 half_t;
typedef _Float16 half8 __attribute__((ext_vector_type(8)));
typedef _Float16 half4v __attribute__((ext_vector_type(4)));
typedef float float4v __attribute__((ext_vector_type(4)));

#define LOG2E 1.44269504088896340736f

#define GLDS16(g, l)                                                                   \
    __builtin_amdgcn_global_load_lds((const __attribute__((address_space(1))) void*)(g), \
                                     (__attribute__((address_space(3))) void*)(l), 16, 0, 0)

// raw barriers: no compiler-inserted vmcnt(0) drain (the __syncthreads trap)
#define BAR_LGKM() __asm__ volatile("s_waitcnt lgkmcnt(0)\n\ts_barrier" ::: "memory")
#define BAR_VM(n)  __asm__ volatile("s_waitcnt vmcnt(" #n ")\n\ts_barrier" ::: "memory")

// ---------------- cast fp32 -> fp16 ----------------
__global__ void cast_f32_f16(const float* __restrict__ in, half_t* __restrict__ out, int n) {
    int i = (blockIdx.x * blockDim.x + threadIdx.x) * 4;
    if (i >= n) return;
    float4 v = *(const float4*)(in + i);
    half4v o;
    o[0] = (half_t)v.x; o[1] = (half_t)v.y; o[2] = (half_t)v.z; o[3] = (half_t)v.w;
    *(half4v*)(out + i) = o;
}

// ---------------- transpose + cast: in fp32 [R][C] -> out fp16 [C][R] ----------------
__global__ void transpose_cast(const float* __restrict__ in, half_t* __restrict__ out, int R, int C) {
    __shared__ float tile[32][33];
    int c0 = blockIdx.x * 32, r0 = blockIdx.y * 32;
    int tx = threadIdx.x, ty = threadIdx.y; // block (32,8)
    for (int p = 0; p < 4; p++) {
        int r = r0 + ty + p * 8;
        tile[ty + p * 8][tx] = in[(size_t)r * C + c0 + tx];
    }
    __syncthreads();
    for (int p = 0; p < 4; p++) {
        int c = c0 + ty + p * 8;
        out[(size_t)c * R + r0 + tx] = (half_t)tile[tx][ty + p * 8];
    }
}

// ---------------- GEMM: C[M][N] = A[M][K] * Bt[N][K]^T + bias ----------------
// 128x128 tile, BK=32, 4 waves; double-buffered global_load_lds with RAW
// barriers — prefetch stays in flight across the barrier (vmcnt(4) mid-loop).
// MODE 0: fp32 out + bias. MODE 1: QKV epilogue — RMSNorm per head (Q pre-scaled
// by LOG2E) -> Qh/Kh head-major; V stored transposed into Vt[bh][d][s].
template <int MODE>
__global__ __launch_bounds__(256) void gemm_f16(
    const half_t* __restrict__ A,   // [M][K]
    const half_t* __restrict__ Bt,  // [N][K]
    const float* __restrict__ bias, // [N]
    void* __restrict__ Cout,
    int M, int N, int K,
    const float* __restrict__ wq, const float* __restrict__ wk,
    half_t* __restrict__ Qh, half_t* __restrict__ Kh)
{
    __shared__ __align__(16) half_t As[2][128 * 32];
    __shared__ __align__(16) half_t Bs[2][128 * 32];
    int t = threadIdx.x;
    int lane = t & 63, w = t >> 6;
    int m0 = blockIdx.x * 128, n0 = blockIdx.y * 128;
    int wm = (w >> 1) * 64, wn = (w & 1) * 64;
    int lrow = lane & 15, quad = lane >> 4;

    const half_t* gA = A  + (size_t)(m0 + (t >> 2)) * K + (t & 3) * 8;
    const half_t* gB = Bt + (size_t)(n0 + (t >> 2)) * K + (t & 3) * 8;
    half_t* ldsA[2] = { &As[0][w * 512], &As[1][w * 512] };
    half_t* ldsB[2] = { &Bs[0][w * 512], &Bs[1][w * 512] };

    float4v acc[4][4] = {};

    // preload tile 0 -> buf 0
    GLDS16(gA,                  ldsA[0]);
    GLDS16(gA + (size_t)64 * K, ldsA[0] + 2048);
    GLDS16(gB,                  ldsB[0]);
    GLDS16(gB + (size_t)64 * K, ldsB[0] + 2048);

    int nk = K >> 5;
    for (int ki = 0; ki < nk; ki++) {
        int cur = ki & 1, nxt = cur ^ 1;
        int k0 = ki << 5;
        BAR_LGKM();                         // everyone done reading buf nxt
        if (ki + 1 < nk) {
            GLDS16(gA + k0 + 32,                  ldsA[nxt]);
            GLDS16(gA + (size_t)64 * K + k0 + 32, ldsA[nxt] + 2048);
            GLDS16(gB + k0 + 32,                  ldsB[nxt]);
            GLDS16(gB + (size_t)64 * K + k0 + 32, ldsB[nxt] + 2048);
            BAR_VM(4);                      // cur landed; nxt stays in flight
        } else {
            BAR_VM(0);
        }
        half8 af[4], bf[4];
        for (int i = 0; i < 4; i++) af[i] = *(const half8*)(&As[cur][(wm + i * 16 + lrow) * 32 + quad * 8]);
        for (int i = 0; i < 4; i++) bf[i] = *(const half8*)(&Bs[cur][(wn + i * 16 + lrow) * 32 + quad * 8]);
        for (int mi = 0; mi < 4; mi++)
            for (int ni = 0; ni < 4; ni++)
                acc[mi][ni] = __builtin_amdgcn_mfma_f32_16x16x32_f16(af[mi], bf[ni], acc[mi][ni], 0, 0, 0);
    }

    if (MODE == 0) {
        float* out = (float*)Cout;
        for (int mi = 0; mi < 4; mi++)
            for (int ni = 0; ni < 4; ni++)
                for (int r = 0; r < 4; r++) {
                    int gr = m0 + wm + mi * 16 + quad * 4 + r;
                    int gc = n0 + wn + ni * 16 + lrow;
                    out[(size_t)gr * N + gc] = acc[mi][ni][r] + bias[gc];
                }
    } else {
        int nglob = n0 + wn;            // 64-aligned; one head per wave
        if (nglob < 2048) {
            int isK = nglob >> 10;
            int h = (nglob >> 6) & 15;
            const float* wv = isK ? wk : wq;
            half_t* dst = isK ? Kh : Qh;
            float post = isK ? 1.0f : LOG2E;   // pre-scale Q so attn works in log2 domain
            for (int mi = 0; mi < 4; mi++)
                for (int r = 0; r < 4; r++) {
                    int gr = m0 + wm + mi * 16 + quad * 4 + r;
                    float v[4]; float ss = 0.f;
                    for (int ni = 0; ni < 4; ni++) {
                        v[ni] = acc[mi][ni][r] + bias[nglob + ni * 16 + lrow];
                        ss += v[ni] * v[ni];
                    }
                    ss += __shfl_xor(ss, 1);
                    ss += __shfl_xor(ss, 2);
                    ss += __shfl_xor(ss, 4);
                    ss += __shfl_xor(ss, 8);
                    float rr = rsqrtf(ss * (1.0f / 64.0f) + 1e-6f) * post;
                    int bb = gr >> 11, s = gr & 2047;
                    size_t rowbase = ((size_t)((bb * 16 + h) * 2048 + s)) * 64;
                    for (int ni = 0; ni < 4; ni++) {
                        int d = ni * 16 + lrow;
                        dst[rowbase + d] = (half_t)(v[ni] * rr * wv[d]);
                    }
                }
        } else {
            // V part: store transposed into Vt[bh][d][s] (4 consecutive s per lane)
            half_t* Vt = (half_t*)Cout;
            for (int mi = 0; mi < 4; mi++) {
                int gr = m0 + wm + mi * 16 + quad * 4;   // s-base, 4-aligned
                int bb = gr >> 11, s = gr & 2047;
                for (int ni = 0; ni < 4; ni++) {
                    int dg = nglob + ni * 16 + lrow - 2048;   // 0..1023
                    float bv = bias[nglob + ni * 16 + lrow];
                    half4v oh;
                    for (int r = 0; r < 4; r++) oh[r] = (half_t)(acc[mi][ni][r] + bv);
                    *(half4v*)(Vt + ((size_t)((bb * 16 + (dg >> 6)) * 64 + (dg & 63))) * 2048 + s) = oh;
                }
            }
        }
    }
}

// ---------------- Flash attention, causal, no scale (Q pre-scaled by LOG2E) --
// 8 waves / 128 q-rows, paired q-tiles (i,15-i), XOR-swizzled LDS,
// grid (bh, pair) for XCD L2 sharing, dbuf K/V with RAW barriers (vmcnt(2)).
__global__ __launch_bounds__(512, 4) void attn(
    const half_t* __restrict__ Qh, const half_t* __restrict__ Kh, const half_t* __restrict__ Vt,
    half_t* __restrict__ Z)
{
    __shared__ __align__(16) half_t Ks[2][64 * 64];   // [buf][key][d], chunk-swizzled
    __shared__ __align__(16) half_t Vs[2][64 * 64];   // [buf][d][key], chunk-swizzled
    __shared__ __align__(16) half_t Ps[8 * 16 * 64];  // per-wave [q][key], chunk-swizzled

    int bh = blockIdx.x;
    int b = bh >> 4, h = bh & 15;
    int t = threadIdx.x, lane = t & 63, w = t >> 6;
    int lrow = lane & 15, quad = lane >> 4;

    int sr = w * 8 + (lane >> 3);
    int scc = (lane & 7) ^ ((lane >> 3) & 7);
    const half_t* gK0 = Kh + ((size_t)bh * 2048 + sr) * 64 + scc * 8;
    const half_t* gV0 = Vt + ((size_t)bh * 64 + sr) * 2048 + scc * 8;

    int sw = lrow & 7;
    int cA = (quad ^ sw) * 8;
    int cB = ((quad + 4) ^ sw) * 8;
    half_t* PsW = Ps + w * 1024 + lrow * 64;

    for (int pass = 0; pass < 2; pass++) {
        int qt = pass ? (15 - (int)blockIdx.y) : (int)blockIdx.y;
        int q0w = qt * 128 + w * 16;

        const half_t* Qbase = Qh + ((size_t)bh * 2048 + q0w + lrow) * 64;
        half8 qf0 = *(const half8*)(Qbase + quad * 8);
        half8 qf1 = *(const half8*)(Qbase + 32 + quad * 8);

        float4v ot[4] = {};
        float m = -__builtin_inff(), l = 0.f;

        int nt = 2 * qt + 2;
        __syncthreads();                      // full drain at pass boundary
        GLDS16(gK0, &Ks[0][w * 512]);
        GLDS16(gV0, &Vs[0][w * 512]);

        for (int kt = 0; kt < nt; kt++) {
            int cur = kt & 1, nxt = cur ^ 1;
            int kb = kt * 64;
            BAR_LGKM();                       // prev readers of buf nxt done
            if (kt + 1 < nt) {
                GLDS16(gK0 + (size_t)(kb + 64) * 64, &Ks[nxt][w * 512]);
                GLDS16(gV0 + kb + 64,                &Vs[nxt][w * 512]);
                BAR_VM(2);                    // cur landed; nxt in flight
            } else {
                BAR_VM(0);
            }
            if (kb > q0w + 15) continue;      // fully masked for this wave

            // S^T = K Q^T (scores already in log2 units): rows=keys, col q=lrow
            float4v st[4];
            for (int f = 0; f < 4; f++) {
                float4v z = {};
                const half_t* kr = &Ks[cur][(f * 16 + lrow) * 64];
                half8 k0 = *(const half8*)(kr + cA);
                half8 k1 = *(const half8*)(kr + cB);
                z = __builtin_amdgcn_mfma_f32_16x16x32_f16(k0, qf0, z, 0, 0, 0);
                z = __builtin_amdgcn_mfma_f32_16x16x32_f16(k1, qf1, z, 0, 0, 0);
                st[f] = z;
            }
            if (kb + 63 > q0w) {              // diagonal-crossing tile
                int qabs = q0w + lrow;
                for (int f = 0; f < 4; f++)
                    for (int r = 0; r < 4; r++) {
                        int key = kb + f * 16 + quad * 4 + r;
                        if (key > qabs) st[f][r] = -__builtin_inff();
                    }
            }
            float tm = st[0][0];
            for (int f = 0; f < 4; f++)
                for (int r = 0; r < 4; r++) tm = fmaxf(tm, st[f][r]);
            tm = fmaxf(tm, __shfl_xor(tm, 16));
            tm = fmaxf(tm, __shfl_xor(tm, 32));
            float mn = fmaxf(m, tm);
            float alpha = __builtin_amdgcn_exp2f(m - mn);
            m = mn;
            float rs = 0.f;
            for (int f = 0; f < 4; f++) {
                float p0 = __builtin_amdgcn_exp2f(st[f][0] - mn);
                float p1 = __builtin_amdgcn_exp2f(st[f][1] - mn);
                float p2 = __builtin_amdgcn_exp2f(st[f][2] - mn);
                float p3 = __builtin_amdgcn_exp2f(st[f][3] - mn);
                rs += (p0 + p1) + (p2 + p3);
                uint2 pw;
                pw.x = __builtin_bit_cast(unsigned, __builtin_amdgcn_cvt_pkrtz(p0, p1));
                pw.y = __builtin_bit_cast(unsigned, __builtin_amdgcn_cvt_pkrtz(p2, p3));
                int cc = (2 * f + (quad >> 1)) ^ sw;
                *(uint2*)(PsW + cc * 8 + (quad & 1) * 4) = pw;
            }
            rs += __shfl_xor(rs, 16);
            rs += __shfl_xor(rs, 32);
            l = l * alpha + rs;
            for (int f2 = 0; f2 < 4; f2++)
                for (int r = 0; r < 4; r++) ot[f2][r] *= alpha;

            __asm__ volatile("s_waitcnt lgkmcnt(0)" ::: "memory");  // P writes visible
            half8 p0v = *(const half8*)(PsW + cA);
            half8 p1v = *(const half8*)(PsW + cB);
            for (int f2 = 0; f2 < 4; f2++) {
                const half_t* vr = &Vs[cur][(f2 * 16 + lrow) * 64];
                half8 v0 = *(const half8*)(vr + cA);
                half8 v1 = *(const half8*)(vr + cB);
                ot[f2] = __builtin_amdgcn_mfma_f32_16x16x32_f16(v0, p0v, ot[f2], 0, 0, 0);
                ot[f2] = __builtin_amdgcn_mfma_f32_16x16x32_f16(v1, p1v, ot[f2], 0, 0, 0);
            }
        }

        float inv = 1.0f / l;
        size_t base = ((size_t)(b * 2048) + q0w + lrow) * 1024 + h * 64;
        for (int f2 = 0; f2 < 4; f2++) {
            half4v oh;
            for (int r = 0; r < 4; r++) oh[r] = (half_t)(ot[f2][r] * inv);
            *(half4v*)(Z + base + f2 * 16 + quad * 4) = oh;
        }
    }
}

// ---------------- launch ----------------
extern "C" void kernel_launch(void* const* d_in, const int* in_sizes, int n_in,
                              void* d_out, int out_size, void* d_ws, size_t ws_size,
                              hipStream_t stream)
{
    const float* x     = (const float*)d_in[0];
    // d_in[1] = mask (causal, known analytically) - unused
    const float* W_qkv = (const float*)d_in[2];
    const float* b_qkv = (const float*)d_in[3];
    const float* W_o   = (const float*)d_in[4];
    const float* b_o   = (const float*)d_in[5];
    const float* wq    = (const float*)d_in[6];
    const float* wk    = (const float*)d_in[7];
    float* out = (float*)d_out;

    char* ws = (char*)d_ws;
    half_t* xh   = (half_t*)(ws);                     // 16 MB (reused as zh after attn)
    half_t* Wqt  = (half_t*)(ws + (16ull << 20));     // 6 MB
    half_t* Wot  = (half_t*)(ws + (22ull << 20));     // 2 MB
    half_t* Qh   = (half_t*)(ws + (40ull << 20));     // 16 MB
    half_t* Kh   = (half_t*)(ws + (56ull << 20));     // 16 MB
    half_t* Vt   = (half_t*)(ws + (72ull << 20));     // 16 MB
    half_t* zh   = xh;

    cast_f32_f16<<<8192, 256, 0, stream>>>(x, xh, 8192 * 1024);
    transpose_cast<<<dim3(96, 32), dim3(32, 8), 0, stream>>>(W_qkv, Wqt, 1024, 3072);
    transpose_cast<<<dim3(32, 32), dim3(32, 8), 0, stream>>>(W_o, Wot, 1024, 1024);
    gemm_f16<1><<<dim3(64, 24), 256, 0, stream>>>(xh, Wqt, b_qkv, Vt, 8192, 3072, 1024,
                                                  wq, wk, Qh, Kh);
    attn<<<dim3(64, 8), 512, 0, stream>>>(Qh, Kh, Vt, zh);
    gemm_f16<0><<<dim3(64, 8), 256, 0, stream>>>(zh, Wot, b_o, out, 8192, 1024, 1024,
                                                 nullptr, nullptr, nullptr, nullptr);
}